// Round 6
// baseline (282.280 us; speedup 1.0000x reference)
//
#include <hip/hip_runtime.h>
#include <hip/hip_bf16.h>
#include <math.h>

// Model constants (fixed by shapes)
#define NEDGE 240
#define NBAT  8
#define MROWS 1920   // NBAT*NEDGE
#define NPTS  256
#define CIN   5

typedef __attribute__((ext_vector_type(8))) short  bf16x8;
typedef __attribute__((ext_vector_type(4))) float  f32x4;

// tanh-form GELU via sigmoid: gelu(x) ~= x * sigmoid(1.5957691*x + 0.07135481*x^3)
__device__ __forceinline__ float gelu_f(float x){
    float x2 = x*x;
    float t  = fmaf(0.07135481f, x2, 1.59576912f);
    float s  = fminf(x*t, 80.f);
    float e  = __expf(s);
    float r  = __builtin_amdgcn_rcpf(e + 1.0f);
    return x*e*r;
}
__device__ __forceinline__ float wave_sum(float v){
    #pragma unroll
    for (int off=32; off>0; off>>=1) v += __shfl_xor(v, off);
    return v;
}
__device__ __forceinline__ unsigned short f2bf(float x){   // RNE f32->bf16
    unsigned int u = __float_as_uint(x);
    return (unsigned short)((u + 0x7FFFu + ((u>>16)&1u)) >> 16);
}
__device__ __forceinline__ unsigned pack_bf2(float lo, float hi){
    __hip_bfloat162 t = __float22bfloat162_rn(make_float2(lo, hi));
    union { __hip_bfloat162 b; unsigned u; } cv; cv.b = t;
    return cv.u;
}

// VALU-pipe 16-lane rotate-reduce (DPP row_ror) — keeps stats off the DS pipe
#define DPP_ADD(v, ctrl) \
    { int _t = __builtin_amdgcn_update_dpp(0, __float_as_int(v), (ctrl), 0xF, 0xF, false); \
      (v) += __int_as_float(_t); }
#define ROW16_SUM(v) { DPP_ADD(v,0x121); DPP_ADD(v,0x122); DPP_ADD(v,0x124); DPP_ADD(v,0x128); }
// ds_swizzle butterfly (BitMode): xor mask<<10 | 0x1F
#define SWZ_ADD(v, patt) \
    (v) += __int_as_float(__builtin_amdgcn_ds_swizzle(__float_as_int(v), (patt)))

// ---------------- K0: pre-convert conv weights to bf16 MFMA A-fragments ----
// frag id f = layer*24 + ob*6 + tap*2 + q ; lane m=lane&15 (out ch in o-block),
// k = 32q + 8*(lane>>4) + e (in ch). wf[(f*64+lane)*8+e]
__global__ __launch_bounds__(256) void k_wprep(
    const float* __restrict__ conv_w, unsigned short* __restrict__ wf)
{
    int t = blockIdx.x*256 + threadIdx.x;
    if (t >= 120*64) return;
    int lane = t & 63, f = t >> 6;
    int q = f & 1, tap = (f>>1)%3, ob = (f/6)&3, layer = f/24;
    int o = 16*ob + (lane&15);
    int ibase = 32*q + 8*(lane>>4);
    #pragma unroll
    for (int e=0;e<8;++e){
        int i = ibase + e;
        float w = conv_w[(((size_t)layer*64 + o)*64 + i)*3 + tap];
        wf[(size_t)t*8 + e] = f2bf(w);
    }
}

// ---------------- K1: stem + 5 residual conv/GN/GELU blocks + mean pool ----
// one block (512 thr) per edge. hbf[n'=0..257][i=0..63] bf16, swizzled chunks.
// MAIN layout: wave w owns ALL 4 o-blocks x 32 cols (colbase=32w, nbl 0..1)
//   -> each B-frag ds_read feeds 4 MFMAs (4x less LDS-read than R5).
// A-frags (8 = 4ob x 2q) in regs, reloaded per tap from global (VMEM/L2).
// GN stats: DPP row-ror reduce (VALU) + xor16 swizzle + 64-thread reducer.
__global__ __launch_bounds__(512, 4) void k_extract(
    const float* __restrict__ edge_data, const float* __restrict__ stem_w,
    const float* __restrict__ stem_b, const unsigned short* __restrict__ wf,
    const float* __restrict__ gn_g, const float* __restrict__ gn_b,
    float* __restrict__ emb0)
{
    __shared__ unsigned short hbf[258*64];    // 33024 B
    __shared__ float redg[2][4][8][2];        // [half][ob][wave][{s,sq}]
    __shared__ float gstat[8][2];             // [group][{mu,rstd}]
    __shared__ float redp[8][4][16];          // pool partials [wave][g][ob*4+j]
    const int m = blockIdx.x, tid = threadIdx.x;
    const int w = tid>>6, lane = tid&63;
    const int g = (lane>>4)&3, l15 = lane&15;
    const int colbase = 32*w;
    const bf16x8* wfp = (const bf16x8*)wf;

    // A-frags layer0/tap0 (issue before stem; land during it)
    bf16x8 A[8];
    #pragma unroll
    for (int a=0;a<8;++a){
        int ob=a>>1, q=a&1;
        A[a] = wfp[(size_t)(ob*6 + q)*64 + lane];
    }

    // ---- loop-invariant LDS addresses (main layout)
    unsigned raddr[3][2];
    {
        unsigned clb = (unsigned)((colbase + l15)*128);
        #pragma unroll
        for (int tap=0;tap<3;++tap)
            #pragma unroll
            for (int q=0;q<2;++q)
                raddr[tap][q] = clb + (unsigned)(((4*q+g) ^ ((l15+tap)&7))<<4);
    }
    unsigned wbase[4];
    #pragma unroll
    for (int ob=0;ob<4;++ob)
        wbase[ob] = (unsigned)((colbase + l15 + 1)*128
                  + (((2*ob + (g>>1)) ^ ((l15+1)&7))<<4) + 8*(g&1));

    // ---- stem in the OLD layout (wave=1 o-block x 128 cols; 20 weight loads)
    {
        const int wbs = w&3, colbase2 = 128*(w>>2);
        const int i0s = 16*wbs + 4*g;
        const unsigned wb0s = (unsigned)((colbase2 + l15 + 1)*128
                            + (((i0s>>3) ^ ((l15+1)&7))<<4) + ((i0s&7)<<1));
        const float* xs = edge_data + (size_t)m*CIN*NPTS;
        float sw_[4][6];
        #pragma unroll
        for (int j=0;j<4;++j){
            int o = i0s + j;
            #pragma unroll
            for (int c=0;c<5;++c) sw_[j][c] = stem_w[c*64+o];
            sw_[j][5] = stem_b[o];
        }
        #pragma unroll
        for (int nbl=0;nbl<8;++nbl){
            int n = colbase2 + 16*nbl + l15;
            float x0=xs[n], x1=xs[NPTS+n], x2=xs[2*NPTS+n],
                  x3=xs[3*NPTS+n], x4=xs[4*NPTS+n];
            float h0 = sw_[0][5] + x0*sw_[0][0] + x1*sw_[0][1] + x2*sw_[0][2] + x3*sw_[0][3] + x4*sw_[0][4];
            float h1 = sw_[1][5] + x0*sw_[1][0] + x1*sw_[1][1] + x2*sw_[1][2] + x3*sw_[1][3] + x4*sw_[1][4];
            float h2 = sw_[2][5] + x0*sw_[2][0] + x1*sw_[2][1] + x2*sw_[2][2] + x3*sw_[2][3] + x4*sw_[2][4];
            float h3 = sw_[3][5] + x0*sw_[3][0] + x1*sw_[3][1] + x2*sw_[3][2] + x3*sw_[3][3] + x4*sw_[3][4];
            unsigned long long pk = (unsigned long long)pack_bf2(h0,h1)
                                  | ((unsigned long long)pack_bf2(h2,h3) << 32);
            *(unsigned long long*)((char*)hbf + wb0s + 2048*nbl) = pk;
        }
    }
    // zero halo rows n'=0 and n'=257
    if (tid < 32)       ((unsigned int*)hbf)[tid] = 0u;
    else if (tid < 64)  ((unsigned int*)hbf)[257*32 + tid - 32] = 0u;
    __syncthreads();

    // ---- h master (f32) init by readback in the MAIN layout
    float h[4][2][4];   // [ob][nbl][j]
    #pragma unroll
    for (int ob=0;ob<4;++ob)
    #pragma unroll
    for (int nbl=0;nbl<2;++nbl){
        unsigned long long v = *(const unsigned long long*)((const char*)hbf + wbase[ob] + 2048*nbl);
        #pragma unroll
        for (int j=0;j<4;++j)
            h[ob][nbl][j] = __uint_as_float(((unsigned)((v>>(16*j)) & 0xFFFFull)) << 16);
    }

    // ---- 5 residual conv blocks
    #pragma unroll 1
    for (int layer=0; layer<5; ++layer){
        f32x4 acc[4][2];
        #pragma unroll
        for (int ob=0;ob<4;++ob)
            #pragma unroll
            for (int nbl=0;nbl<2;++nbl) acc[ob][nbl] = (f32x4){0.f,0.f,0.f,0.f};

        #pragma unroll
        for (int tap=0; tap<3; ++tap){
            #pragma unroll
            for (int q=0; q<2; ++q)
            #pragma unroll
            for (int nbl=0; nbl<2; ++nbl){
                bf16x8 Bv = *(const bf16x8*)((const char*)hbf
                              + raddr[tap][q] + (2048*nbl + 128*tap));
                #pragma unroll
                for (int ob=0; ob<4; ++ob)
                    acc[ob][nbl] = __builtin_amdgcn_mfma_f32_16x16x32_bf16(
                                       A[ob*2+q], Bv, acc[ob][nbl], 0,0,0);
            }
            if (tap < 2){   // reload A for next tap (VMEM; after last use)
                #pragma unroll
                for (int a=0;a<8;++a){
                    int ob=a>>1, q=a&1;
                    A[a] = wfp[(size_t)(layer*24 + ob*6 + (tap+1)*2 + q)*64 + lane];
                }
            }
        }

        // GroupNorm partials: group(ob) = 2*ob + (g>>1); half = lane>>5
        float s[4], sq[4];
        #pragma unroll
        for (int ob=0;ob<4;++ob){
            float a=0.f, b=0.f;
            #pragma unroll
            for (int nbl=0;nbl<2;++nbl)
                #pragma unroll
                for (int j=0;j<4;++j){ float v=acc[ob][nbl][j]; a+=v; b+=v*v; }
            s[ob]=a; sq[ob]=b;
        }
        #pragma unroll
        for (int ob=0;ob<4;++ob){ ROW16_SUM(s[ob]); ROW16_SUM(sq[ob]); }
        #pragma unroll
        for (int ob=0;ob<4;++ob){ SWZ_ADD(s[ob],0x401F); SWZ_ADD(sq[ob],0x401F); }
        if ((lane&31)==0){
            int half = lane>>5;
            #pragma unroll
            for (int ob=0;ob<4;++ob){
                redg[half][ob][w][0] = s[ob];
                redg[half][ob][w][1] = sq[ob];
            }
        }
        __syncthreads();   // #1: MFMA reads of hbf done; redg published

        if (tid < 64){     // reducer: 8 lanes per group
            int gr = tid>>3, widx = tid&7;
            float ss = redg[gr&1][gr>>1][widx][0];
            float qq = redg[gr&1][gr>>1][widx][1];
            SWZ_ADD(ss,0x041F); SWZ_ADD(qq,0x041F);
            SWZ_ADD(ss,0x081F); SWZ_ADD(qq,0x081F);
            SWZ_ADD(ss,0x101F); SWZ_ADD(qq,0x101F);
            if (widx==0){
                float mu = ss*(1.f/2048.f);
                gstat[gr][0] = mu;
                gstat[gr][1] = rsqrtf(qq*(1.f/2048.f) - mu*mu + 1e-5f);
            }
        }
        __syncthreads();   // #2: gstat ready

        // epilogue: GN (folded) + gelu + residual; gamma/beta via global float4
        #pragma unroll
        for (int ob=0;ob<4;++ob){
            float4 gv = *(const float4*)(gn_g + layer*64 + 16*ob + 4*g);
            float4 bv = *(const float4*)(gn_b + layer*64 + 16*ob + 4*g);
            float mu = gstat[2*ob+(g>>1)][0], rstd = gstat[2*ob+(g>>1)][1];
            float K1x = rstd*gv.x, K1y = rstd*gv.y, K1z = rstd*gv.z, K1w = rstd*gv.w;
            float K2x = fmaf(-mu,K1x,bv.x), K2y = fmaf(-mu,K1y,bv.y),
                  K2z = fmaf(-mu,K1z,bv.z), K2w = fmaf(-mu,K1w,bv.w);
            #pragma unroll
            for (int nbl=0;nbl<2;++nbl){
                h[ob][nbl][0] += gelu_f(fmaf(acc[ob][nbl][0], K1x, K2x));
                h[ob][nbl][1] += gelu_f(fmaf(acc[ob][nbl][1], K1y, K2y));
                h[ob][nbl][2] += gelu_f(fmaf(acc[ob][nbl][2], K1z, K2z));
                h[ob][nbl][3] += gelu_f(fmaf(acc[ob][nbl][3], K1w, K2w));
            }
        }
        if (layer < 4){
            #pragma unroll
            for (int ob=0;ob<4;++ob)
            #pragma unroll
            for (int nbl=0;nbl<2;++nbl){
                unsigned long long pk = (unsigned long long)pack_bf2(h[ob][nbl][0],h[ob][nbl][1])
                                      | ((unsigned long long)pack_bf2(h[ob][nbl][2],h[ob][nbl][3]) << 32);
                *(unsigned long long*)((char*)hbf + wbase[ob] + 2048*nbl) = pk;
            }
            // next layer tap-0 A-frags (land during barrier + next MFMA ramp)
            #pragma unroll
            for (int a=0;a<8;++a){
                int ob=a>>1, q=a&1;
                A[a] = wfp[(size_t)((layer+1)*24 + ob*6 + q)*64 + lane];
            }
            __syncthreads();   // #3: hbf ready for next layer
        }
    }

    // ---- mean pool over N
    float p[4][4];
    #pragma unroll
    for (int ob=0;ob<4;++ob)
        #pragma unroll
        for (int j=0;j<4;++j){
            float v = h[ob][0][j] + h[ob][1][j];
            ROW16_SUM(v);
            p[ob][j] = v;
        }
    if (l15==0){
        #pragma unroll
        for (int ob=0;ob<4;++ob)
            #pragma unroll
            for (int j=0;j<4;++j) redp[w][g][ob*4+j] = p[ob][j];
    }
    __syncthreads();
    if (tid < 64){
        int ob = tid>>4, gg = (tid>>2)&3, j = tid&3;
        float sum = 0.f;
        #pragma unroll
        for (int ww=0;ww<8;++ww) sum += redp[ww][gg][ob*4+j];
        emb0[(size_t)m*64+tid] = sum * (1.0f/256.0f);
    }
}

// ---------------- K2: merge (concat @ em_w -> LN -> gelu) + qkv (layer 0) --
__global__ __launch_bounds__(256) void k_mergeqkv(
    const float* __restrict__ emb0, const int* __restrict__ edge_types,
    const float* __restrict__ type_emb, const float* __restrict__ em_w,
    const float* __restrict__ em_b, const float* __restrict__ em_g,
    const float* __restrict__ em_bt, const float* __restrict__ wqkv,
    const float* __restrict__ bqkv, float* __restrict__ emb,
    float* __restrict__ qkv)
{
    int m  = blockIdx.x*4 + (threadIdx.x>>6);
    int ln = threadIdx.x & 63;
    float a = emb0[(size_t)m*64+ln];
    int ty = edge_types[m];
    float tb = type_emb[ty*64+ln];
    float va = 0.f, vb = 0.f;
    for (int j=0;j<64;++j) va += __shfl(a,j)  * em_w[j*64+ln];
    for (int j=0;j<64;++j) vb += __shfl(tb,j) * em_w[(64+j)*64+ln];
    float v = em_b[ln] + va + vb;
    float mu  = wave_sum(v)*(1.0f/64.0f);
    float d   = v - mu;
    float var = wave_sum(d*d)*(1.0f/64.0f);
    float e = gelu_f(d * rsqrtf(var+1e-5f) * em_g[ln] + em_bt[ln]);
    emb[(size_t)m*64+ln] = e;
    float q = bqkv[ln], k = bqkv[64+ln], vv = bqkv[128+ln];
    for (int j=0;j<64;++j){
        float ej = __shfl(e,j);
        q  += ej*wqkv[j*192+ln];
        k  += ej*wqkv[j*192+64+ln];
        vv += ej*wqkv[j*192+128+ln];
    }
    qkv[(size_t)m*192+ln]=q; qkv[(size_t)m*192+64+ln]=k; qkv[(size_t)m*192+128+ln]=vv;
}

// ---------------- K3: attention; block = (batch, head, qtile of 64) ---------
__global__ __launch_bounds__(256) void k_attn(
    const float* __restrict__ qkv, float* __restrict__ o)
{
    __shared__ float KsT[16][244], VsT[16][244];
    int blk = blockIdx.x;
    int b  = blk >> 4;
    int h  = (blk >> 2) & 3;
    int qt = blk & 3;
    int tid = threadIdx.x;
    for (int i=tid; i<NEDGE*16; i+=256){
        int r = i>>4, d = i&15;
        size_t base = ((size_t)(b*NEDGE+r))*192 + h*16 + d;
        KsT[d][r] = qkv[base+64];
        VsT[d][r] = qkv[base+128];
    }
    __syncthreads();
    int c = tid & 3, qi = tid >> 2;
    int q = qt*64 + qi;
    bool act = (q < NEDGE);
    float qv[16];
    size_t qb = ((size_t)(b*NEDGE + (act ? q : 0)))*192 + h*16;
    #pragma unroll
    for (int d=0; d<16; ++d) qv[d] = qkv[qb+d];
    float mx = -3e38f, l = 0.f, acc[16];
    #pragma unroll
    for (int d=0; d<16; ++d) acc[d]=0.f;
    for (int k=0; k<60; ++k){
        int key = 60*c + k;
        float s=0.f;
        #pragma unroll
        for (int d=0; d<16; ++d) s += qv[d]*KsT[d][key];
        s *= 0.25f;
        if (s > mx){
            float so = __expf(mx - s);
            l *= so;
            #pragma unroll
            for (int d=0; d<16; ++d) acc[d] *= so;
            mx = s;
        }
        float pp = __expf(s - mx);
        l += pp;
        #pragma unroll
        for (int d=0; d<16; ++d) acc[d] = fmaf(pp, VsT[d][key], acc[d]);
    }
    #pragma unroll
    for (int off=1; off<=2; off<<=1){
        float mo = __shfl_xor(mx, off);
        float lo = __shfl_xor(l,  off);
        float M  = fmaxf(mx, mo);
        float ss = __expf(mx - M);
        float so = __expf(mo - M);
        l = l*ss + lo*so;
        #pragma unroll
        for (int d=0; d<16; ++d)
            acc[d] = acc[d]*ss + __shfl_xor(acc[d], off)*so;
        mx = M;
    }
    if (act && c==0){
        float inv = 1.f/l;
        size_t obase = ((size_t)(b*NEDGE+q))*64 + h*16;
        #pragma unroll
        for (int d=0; d<16; ++d) o[obase+d] = acc[d]*inv;
    }
}

// ---------------- K4: out-proj+LN1+FFN+LN2 (+ optional next-layer qkv) ------
__global__ __launch_bounds__(256) void k_postattn(
    const float* __restrict__ o, const float* __restrict__ wo,
    const float* __restrict__ bo, const float* __restrict__ g1,
    const float* __restrict__ b1ln, const float* __restrict__ w1,
    const float* __restrict__ b1, const float* __restrict__ w2,
    const float* __restrict__ b2, const float* __restrict__ g2,
    const float* __restrict__ b2ln, float* __restrict__ emb,
    const float* __restrict__ wqkv, const float* __restrict__ bqkv,
    float* __restrict__ qkv)
{
    int m  = blockIdx.x*4 + (threadIdx.x>>6);
    int ln = threadIdx.x & 63;
    float ov = o[(size_t)m*64+ln];
    float r = bo[ln];
    for (int j=0;j<64;++j) r += __shfl(ov,j)*wo[j*64+ln];
    float x = emb[(size_t)m*64+ln] + r;
    float mu  = wave_sum(x)*(1.f/64.f);
    float d   = x-mu;
    float var = wave_sum(d*d)*(1.f/64.f);
    float e1 = d*rsqrtf(var+1e-5f)*g1[ln] + b1ln[ln];
    float4 bv = *(const float4*)(b1 + ln*4);
    float h[4] = {bv.x, bv.y, bv.z, bv.w};
    for (int j=0;j<64;++j){
        float ej = __shfl(e1,j);
        float4 wv = *(const float4*)(w1 + j*256 + ln*4);
        h[0] += ej*wv.x; h[1] += ej*wv.y; h[2] += ej*wv.z; h[3] += ej*wv.w;
    }
    #pragma unroll
    for (int u=0;u<4;++u) h[u]=gelu_f(h[u]);
    float f0=0.f, f1=0.f, f2=0.f, f3=0.f;
    for (int j=0;j<64;++j){
        f0 += __shfl(h[0],j) * w2[(j*4+0)*64+ln];
        f1 += __shfl(h[1],j) * w2[(j*4+1)*64+ln];
        f2 += __shfl(h[2],j) * w2[(j*4+2)*64+ln];
        f3 += __shfl(h[3],j) * w2[(j*4+3)*64+ln];
    }
    float f = b2[ln] + ((f0+f1)+(f2+f3));
    float x2 = e1 + f;
    float mu2  = wave_sum(x2)*(1.f/64.f);
    float d2   = x2-mu2;
    float var2 = wave_sum(d2*d2)*(1.f/64.f);
    float e2 = d2*rsqrtf(var2+1e-5f)*g2[ln] + b2ln[ln];
    emb[(size_t)m*64+ln] = e2;
    if (wqkv){
        float q = bqkv[ln], k = bqkv[64+ln], vv = bqkv[128+ln];
        for (int j=0;j<64;++j){
            float ej = __shfl(e2,j);
            q  += ej*wqkv[j*192+ln];
            k  += ej*wqkv[j*192+64+ln];
            vv += ej*wqkv[j*192+128+ln];
        }
        qkv[(size_t)m*192+ln]=q; qkv[(size_t)m*192+64+ln]=k; qkv[(size_t)m*192+128+ln]=vv;
    }
}

// ---------------- K5: edge head + node head fused ---------------------------
__global__ __launch_bounds__(256) void k_heads(
    const float* __restrict__ emb, const float* __restrict__ eh_w,
    const float* __restrict__ eh_b, const float* __restrict__ nm_w,
    const float* __restrict__ nm_b, const float* __restrict__ nm_g,
    const float* __restrict__ nm_bt, const float* __restrict__ nh_w,
    const float* __restrict__ nh_b, const int* __restrict__ pp,
    const int* __restrict__ xp, const int* __restrict__ yp,
    float* __restrict__ out)
{
    if (blockIdx.x < 15){
        int gid = blockIdx.x*256 + threadIdx.x;
        int m = gid>>1, c = gid&1;
        float s = eh_b[c];
        const float* e = emb + (size_t)m*64;
        #pragma unroll 8
        for (int j=0;j<64;++j) s += e[j]*eh_w[j*2+c];
        out[gid] = s;
        return;
    }
    int wid = (blockIdx.x-15)*4 + (threadIdx.x>>6);
    int ln  = threadIdx.x & 63;
    int p = pp[0], xi = xp[0], yi = yp[0];
    int nu = p-2;
    if (wid >= NBAT*nu) return;
    int b = wid / nu, r = wid % nu;
    int u=-1, cnt=0;
    for (int i=0;i<p;++i){ if (i!=xi && i!=yi){ if (cnt==r){u=i;break;} ++cnt; } }
    #define EIDX(a,v) ((a)*(p-1) + (v) - (((v)>(a))?1:0))
    int iux = EIDX(u,xi), iuy = EIDX(u,yi), ixu = EIDX(xi,u), iyu = EIDX(yi,u);
    float g0 = emb[((size_t)(b*NEDGE+iux))*64+ln];
    float g1 = emb[((size_t)(b*NEDGE+iuy))*64+ln];
    float g2 = emb[((size_t)(b*NEDGE+ixu))*64+ln];
    float g3 = emb[((size_t)(b*NEDGE+iyu))*64+ln];
    float v = nm_b[ln];
    for (int j=0;j<64;++j) v += __shfl(g0,j)*nm_w[j*64+ln];
    for (int j=0;j<64;++j) v += __shfl(g1,j)*nm_w[(64+j)*64+ln];
    for (int j=0;j<64;++j) v += __shfl(g2,j)*nm_w[(128+j)*64+ln];
    for (int j=0;j<64;++j) v += __shfl(g3,j)*nm_w[(192+j)*64+ln];
    float mu  = wave_sum(v)*(1.f/64.f);
    float d   = v-mu;
    float var = wave_sum(d*d)*(1.f/64.f);
    float node = gelu_f(d*rsqrtf(var+1e-5f)*nm_g[ln] + nm_bt[ln]);
    float pl[8];
    #pragma unroll
    for (int c=0;c<8;++c) pl[c] = node*nh_w[ln*8+c];
    #pragma unroll
    for (int off=32; off>0; off>>=1)
        #pragma unroll
        for (int c=0;c<8;++c) pl[c] += __shfl_xor(pl[c], off);
    if (ln==0){
        #pragma unroll
        for (int c=0;c<8;++c) out[MROWS*2 + ((size_t)wid)*8 + c] = pl[c] + nh_b[c];
    }
}

extern "C" void kernel_launch(void* const* d_in, const int* in_sizes, int n_in,
                              void* d_out, int out_size, void* d_ws, size_t ws_size,
                              hipStream_t stream)
{
    const float* edge_data = (const float*)d_in[0];
    const int*   edge_types= (const int*)d_in[1];
    const int* pp = (const int*)d_in[3];
    const int* xp = (const int*)d_in[4];
    const int* yp = (const int*)d_in[5];
    const float* stem_w=(const float*)d_in[6];
    const float* stem_b=(const float*)d_in[7];
    const float* conv_w=(const float*)d_in[8];
    const float* gn_g=(const float*)d_in[9];
    const float* gn_b=(const float*)d_in[10];
    const float* type_emb=(const float*)d_in[11];
    const float* em_w=(const float*)d_in[12];
    const float* em_b=(const float*)d_in[13];
    const float* em_g=(const float*)d_in[14];
    const float* em_bt=(const float*)d_in[15];
    const float* a_wqkv=(const float*)d_in[16];
    const float* a_bqkv=(const float*)d_in[17];
    const float* a_wo=(const float*)d_in[18];
    const float* a_bo=(const float*)d_in[19];
    const float* ln1_g=(const float*)d_in[20];
    const float* ln1_b=(const float*)d_in[21];
    const float* ff_w1=(const float*)d_in[22];
    const float* ff_b1=(const float*)d_in[23];
    const float* ff_w2=(const float*)d_in[24];
    const float* ff_b2=(const float*)d_in[25];
    const float* ln2_g=(const float*)d_in[26];
    const float* ln2_b=(const float*)d_in[27];
    const float* eh_w=(const float*)d_in[28];
    const float* eh_b=(const float*)d_in[29];
    const float* nm_w=(const float*)d_in[30];
    const float* nm_b=(const float*)d_in[31];
    const float* nm_g=(const float*)d_in[32];
    const float* nm_bt=(const float*)d_in[33];
    const float* nh_w=(const float*)d_in[34];
    const float* nh_b=(const float*)d_in[35];
    (void)in_sizes; (void)n_in; (void)out_size; (void)ws_size;

    unsigned short* wfrag = (unsigned short*)d_ws;
    float* wsf  = (float*)d_ws;
    float* emb  = wsf + 30720;
    float* qkvb = emb + 122880;
    float* obuf = qkvb + 368640;
    float* outp = (float*)d_out;

    k_wprep   <<<30, 256, 0, stream>>>(conv_w, wfrag);
    k_extract <<<MROWS, 512, 0, stream>>>(edge_data, stem_w, stem_b, wfrag, gn_g, gn_b, emb);
    k_mergeqkv<<<MROWS/4, 256, 0, stream>>>(emb, edge_types, type_emb, em_w, em_b, em_g,
                                            em_bt, a_wqkv, a_bqkv, emb, qkvb);
    // layer 0
    k_attn    <<<NBAT*16, 256, 0, stream>>>(qkvb, obuf);
    k_postattn<<<MROWS/4, 256, 0, stream>>>(obuf, a_wo, a_bo, ln1_g, ln1_b,
                                            ff_w1, ff_b1, ff_w2, ff_b2, ln2_g, ln2_b,
                                            emb, a_wqkv + (size_t)64*192, a_bqkv + 192, qkvb);
    // layer 1
    k_attn    <<<NBAT*16, 256, 0, stream>>>(qkvb, obuf);
    k_postattn<<<MROWS/4, 256, 0, stream>>>(obuf, a_wo + (size_t)64*64, a_bo + 64,
                                            ln1_g + 64, ln1_b + 64,
                                            ff_w1 + (size_t)64*256, ff_b1 + 256,
                                            ff_w2 + (size_t)256*64, ff_b2 + 64,
                                            ln2_g + 64, ln2_b + 64,
                                            emb, (const float*)nullptr, (const float*)nullptr, qkvb);
    k_heads   <<<43, 256, 0, stream>>>(emb, eh_w, eh_b, nm_w, nm_b, nm_g, nm_bt,
                                       nh_w, nh_b, pp, xp, yp, outp);
}

// Round 7
// 280.525 us; speedup vs baseline: 1.0063x; 1.0063x over previous
//
#include <hip/hip_runtime.h>
#include <hip/hip_bf16.h>
#include <math.h>

// Model constants (fixed by shapes)
#define NEDGE 240
#define NBAT  8
#define MROWS 1920   // NBAT*NEDGE
#define NPTS  256
#define CIN   5

typedef __attribute__((ext_vector_type(8))) short  bf16x8;
typedef __attribute__((ext_vector_type(4))) float  f32x4;

// tanh-form GELU via sigmoid: gelu(x) ~= x * sigmoid(1.5957691*x + 0.07135481*x^3)
__device__ __forceinline__ float gelu_f(float x){
    float x2 = x*x;
    float t  = fmaf(0.07135481f, x2, 1.59576912f);
    float s  = fminf(x*t, 80.f);
    float e  = __expf(s);
    float r  = __builtin_amdgcn_rcpf(e + 1.0f);
    return x*e*r;
}
__device__ __forceinline__ float wave_sum(float v){
    #pragma unroll
    for (int off=32; off>0; off>>=1) v += __shfl_xor(v, off);
    return v;
}
__device__ __forceinline__ unsigned short f2bf(float x){   // RNE f32->bf16
    unsigned int u = __float_as_uint(x);
    return (unsigned short)((u + 0x7FFFu + ((u>>16)&1u)) >> 16);
}
__device__ __forceinline__ unsigned pack_bf2(float lo, float hi){
    __hip_bfloat162 t = __float22bfloat162_rn(make_float2(lo, hi));
    union { __hip_bfloat162 b; unsigned u; } cv; cv.b = t;
    return cv.u;
}

// VALU-pipe 16-lane rotate-reduce (DPP row_ror) — keeps stats off the DS pipe
#define DPP_ADD(v, ctrl) \
    { int _t = __builtin_amdgcn_update_dpp(0, __float_as_int(v), (ctrl), 0xF, 0xF, false); \
      (v) += __int_as_float(_t); }
#define ROW16_SUM(v) { DPP_ADD(v,0x121); DPP_ADD(v,0x122); DPP_ADD(v,0x124); DPP_ADD(v,0x128); }
// ds_swizzle butterfly (BitMode): xor mask<<10 | 0x1F
#define SWZ_ADD(v, patt) \
    (v) += __int_as_float(__builtin_amdgcn_ds_swizzle(__float_as_int(v), (patt)))

// ---------------- K0: pre-convert conv weights to bf16 MFMA A-fragments ----
// frag id f = layer*24 + ob*6 + tap*2 + q ; lane m=lane&15 (out ch in o-block),
// k = 32q + 8*(lane>>4) + e (in ch). wf[(f*64+lane)*8+e]
__global__ __launch_bounds__(256) void k_wprep(
    const float* __restrict__ conv_w, unsigned short* __restrict__ wf)
{
    int t = blockIdx.x*256 + threadIdx.x;
    if (t >= 120*64) return;
    int lane = t & 63, f = t >> 6;
    int q = f & 1, tap = (f>>1)%3, ob = (f/6)&3, layer = f/24;
    int o = 16*ob + (lane&15);
    int ibase = 32*q + 8*(lane>>4);
    #pragma unroll
    for (int e=0;e<8;++e){
        int i = ibase + e;
        float w = conv_w[(((size_t)layer*64 + o)*64 + i)*3 + tap];
        wf[(size_t)t*8 + e] = f2bf(w);
    }
}

// ---------------- K1: stem + 5 residual conv/GN/GELU blocks + mean pool ----
// one block (512 thr) per edge. hbf[n'=0..257][i=0..63] bf16, swizzled chunks.
// MAIN layout: wave w owns ALL 4 o-blocks x 32 cols (colbase=32w, nbl 0..1)
//   -> each B-frag ds_read feeds 4 MFMAs.
// A-frags (8 = 4ob x 2q) in regs, reloaded per tap from global (VMEM/L2).
// GN stats: DPP row-ror (VALU) + xor32 swizzle + 64-thread swizzle reducer.
// NOTE: __launch_bounds__(512,2) — (512,4) caps VGPR at 64 and spills (R6).
__global__ __launch_bounds__(512, 2) void k_extract(
    const float* __restrict__ edge_data, const float* __restrict__ stem_w,
    const float* __restrict__ stem_b, const unsigned short* __restrict__ wf,
    const float* __restrict__ gn_g, const float* __restrict__ gn_b,
    float* __restrict__ emb0)
{
    __shared__ unsigned short hbf[258*64];    // 33024 B
    __shared__ float redg[2][4][8][2];        // [half][ob][wave][{s,sq}]
    __shared__ float gstat[8][2];             // [group][{mu,rstd}]
    __shared__ float redp[8][4][16];          // pool partials [wave][g][ob*4+j]
    __shared__ float stw[384];                // stem_w (320) ++ stem_b (64)
    const int m = blockIdx.x, tid = threadIdx.x;
    const int w = tid>>6, lane = tid&63;
    const int g = (lane>>4)&3, l15 = lane&15;
    const int colbase = 32*w;
    const bf16x8* wfp = (const bf16x8*)wf;

    // A-frags layer0/tap0 (issue before stem; land during it)
    bf16x8 A[8];
    #pragma unroll
    for (int a=0;a<8;++a){
        int ob=a>>1, q=a&1;
        A[a] = wfp[(size_t)(ob*6 + q)*64 + lane];
    }

    // stage stem weights; zero halo rows n'=0, n'=257
    if (tid < 384) stw[tid] = (tid < 320) ? stem_w[tid] : stem_b[tid-320];
    if (tid < 32)       ((unsigned int*)hbf)[tid] = 0u;
    else if (tid < 64)  ((unsigned int*)hbf)[257*32 + tid - 32] = 0u;

    // ---- loop-invariant LDS addresses (main layout)
    unsigned raddr[3][2];
    {
        unsigned clb = (unsigned)((colbase + l15)*128);
        #pragma unroll
        for (int tap=0;tap<3;++tap)
            #pragma unroll
            for (int q=0;q<2;++q)
                raddr[tap][q] = clb + (unsigned)(((4*q+g) ^ ((l15+tap)&7))<<4);
    }
    unsigned wbase[4];
    #pragma unroll
    for (int ob=0;ob<4;++ob)
        wbase[ob] = (unsigned)((colbase + l15 + 1)*128
                  + (((2*ob + (g>>1)) ^ ((l15+1)&7))<<4) + 8*(g&1));

    __syncthreads();   // stw ready

    // ---- stem in MAIN layout: exact f32 h master (no bf16 round-trip)
    float h[4][2][4];   // [ob][nbl][j]
    {
        const float* xs = edge_data + (size_t)m*CIN*NPTS;
        float xv[2][5];
        #pragma unroll
        for (int nbl=0;nbl<2;++nbl){
            int n = colbase + 16*nbl + l15;
            #pragma unroll
            for (int c=0;c<5;++c) xv[nbl][c] = xs[c*NPTS + n];
        }
        #pragma unroll
        for (int ob=0;ob<4;++ob){
            #pragma unroll
            for (int j=0;j<4;++j){
                int o = 16*ob + 4*g + j;
                float w0=stw[o], w1=stw[64+o], w2=stw[128+o],
                      w3=stw[192+o], w4=stw[256+o], sb=stw[320+o];
                #pragma unroll
                for (int nbl=0;nbl<2;++nbl)
                    h[ob][nbl][j] = sb + xv[nbl][0]*w0 + xv[nbl][1]*w1
                                  + xv[nbl][2]*w2 + xv[nbl][3]*w3 + xv[nbl][4]*w4;
            }
            #pragma unroll
            for (int nbl=0;nbl<2;++nbl){
                unsigned long long pk = (unsigned long long)pack_bf2(h[ob][nbl][0],h[ob][nbl][1])
                                      | ((unsigned long long)pack_bf2(h[ob][nbl][2],h[ob][nbl][3]) << 32);
                *(unsigned long long*)((char*)hbf + wbase[ob] + 2048*nbl) = pk;
            }
        }
    }
    __syncthreads();   // hbf ready

    // ---- 5 residual conv blocks
    #pragma unroll 1
    for (int layer=0; layer<5; ++layer){
        f32x4 acc[4][2];
        #pragma unroll
        for (int ob=0;ob<4;++ob)
            #pragma unroll
            for (int nbl=0;nbl<2;++nbl) acc[ob][nbl] = (f32x4){0.f,0.f,0.f,0.f};

        #pragma unroll
        for (int tap=0; tap<3; ++tap){
            #pragma unroll
            for (int q=0; q<2; ++q)
            #pragma unroll
            for (int nbl=0; nbl<2; ++nbl){
                bf16x8 Bv = *(const bf16x8*)((const char*)hbf
                              + raddr[tap][q] + (2048*nbl + 128*tap));
                #pragma unroll
                for (int ob=0; ob<4; ++ob)
                    acc[ob][nbl] = __builtin_amdgcn_mfma_f32_16x16x32_bf16(
                                       A[ob*2+q], Bv, acc[ob][nbl], 0,0,0);
            }
            if (tap < 2){   // reload A for next tap (VMEM; after last use)
                #pragma unroll
                for (int a=0;a<8;++a){
                    int ob=a>>1, q=a&1;
                    A[a] = wfp[(size_t)(layer*24 + ob*6 + (tap+1)*2 + q)*64 + lane];
                }
            }
        }

        // GroupNorm partials: group(ob) = 2*ob + (g>>1); half = lane>>5
        float s[4], sq[4];
        #pragma unroll
        for (int ob=0;ob<4;++ob){
            float a=0.f, b=0.f;
            #pragma unroll
            for (int nbl=0;nbl<2;++nbl)
                #pragma unroll
                for (int j=0;j<4;++j){ float v=acc[ob][nbl][j]; a+=v; b+=v*v; }
            s[ob]=a; sq[ob]=b;
        }
        #pragma unroll
        for (int ob=0;ob<4;++ob){ ROW16_SUM(s[ob]); ROW16_SUM(sq[ob]); }
        #pragma unroll
        for (int ob=0;ob<4;++ob){ SWZ_ADD(s[ob],0x401F); SWZ_ADD(sq[ob],0x401F); }
        if ((lane&31)==0){
            int half = lane>>5;
            #pragma unroll
            for (int ob=0;ob<4;++ob){
                redg[half][ob][w][0] = s[ob];
                redg[half][ob][w][1] = sq[ob];
            }
        }
        __syncthreads();   // #1: MFMA reads of hbf done; redg published

        if (tid < 64){     // reducer: 8 lanes per group; gr = 2*ob + half
            int gr = tid>>3, widx = tid&7;
            float ss = redg[gr&1][gr>>1][widx][0];
            float qq = redg[gr&1][gr>>1][widx][1];
            SWZ_ADD(ss,0x041F); SWZ_ADD(qq,0x041F);
            SWZ_ADD(ss,0x081F); SWZ_ADD(qq,0x081F);
            SWZ_ADD(ss,0x101F); SWZ_ADD(qq,0x101F);
            if (widx==0){
                float mu = ss*(1.f/2048.f);
                gstat[gr][0] = mu;
                gstat[gr][1] = rsqrtf(qq*(1.f/2048.f) - mu*mu + 1e-5f);
            }
        }
        __syncthreads();   // #2: gstat ready

        // epilogue: GN (folded) + gelu + residual; gamma/beta via global float4
        #pragma unroll
        for (int ob=0;ob<4;++ob){
            float4 gv = *(const float4*)(gn_g + layer*64 + 16*ob + 4*g);
            float4 bv = *(const float4*)(gn_b + layer*64 + 16*ob + 4*g);
            float mu = gstat[2*ob+(g>>1)][0], rstd = gstat[2*ob+(g>>1)][1];
            float K1x = rstd*gv.x, K1y = rstd*gv.y, K1z = rstd*gv.z, K1w = rstd*gv.w;
            float K2x = fmaf(-mu,K1x,bv.x), K2y = fmaf(-mu,K1y,bv.y),
                  K2z = fmaf(-mu,K1z,bv.z), K2w = fmaf(-mu,K1w,bv.w);
            #pragma unroll
            for (int nbl=0;nbl<2;++nbl){
                h[ob][nbl][0] += gelu_f(fmaf(acc[ob][nbl][0], K1x, K2x));
                h[ob][nbl][1] += gelu_f(fmaf(acc[ob][nbl][1], K1y, K2y));
                h[ob][nbl][2] += gelu_f(fmaf(acc[ob][nbl][2], K1z, K2z));
                h[ob][nbl][3] += gelu_f(fmaf(acc[ob][nbl][3], K1w, K2w));
            }
        }
        if (layer < 4){
            #pragma unroll
            for (int ob=0;ob<4;++ob)
            #pragma unroll
            for (int nbl=0;nbl<2;++nbl){
                unsigned long long pk = (unsigned long long)pack_bf2(h[ob][nbl][0],h[ob][nbl][1])
                                      | ((unsigned long long)pack_bf2(h[ob][nbl][2],h[ob][nbl][3]) << 32);
                *(unsigned long long*)((char*)hbf + wbase[ob] + 2048*nbl) = pk;
            }
            // next layer tap-0 A-frags (land during barrier + next MFMA ramp)
            #pragma unroll
            for (int a=0;a<8;++a){
                int ob=a>>1, q=a&1;
                A[a] = wfp[(size_t)((layer+1)*24 + ob*6 + q)*64 + lane];
            }
            __syncthreads();   // #3: hbf ready for next layer
        }
    }

    // ---- mean pool over N
    float p[4][4];
    #pragma unroll
    for (int ob=0;ob<4;++ob)
        #pragma unroll
        for (int j=0;j<4;++j){
            float v = h[ob][0][j] + h[ob][1][j];
            ROW16_SUM(v);
            p[ob][j] = v;
        }
    if (l15==0){
        #pragma unroll
        for (int ob=0;ob<4;++ob)
            #pragma unroll
            for (int j=0;j<4;++j) redp[w][g][ob*4+j] = p[ob][j];
    }
    __syncthreads();
    if (tid < 64){
        int ob = tid>>4, gg = (tid>>2)&3, j = tid&3;
        float sum = 0.f;
        #pragma unroll
        for (int ww=0;ww<8;++ww) sum += redp[ww][gg][ob*4+j];
        emb0[(size_t)m*64+tid] = sum * (1.0f/256.0f);
    }
}

// ---------------- K2: merge (concat @ em_w -> LN -> gelu) + qkv (layer 0) --
__global__ __launch_bounds__(256) void k_mergeqkv(
    const float* __restrict__ emb0, const int* __restrict__ edge_types,
    const float* __restrict__ type_emb, const float* __restrict__ em_w,
    const float* __restrict__ em_b, const float* __restrict__ em_g,
    const float* __restrict__ em_bt, const float* __restrict__ wqkv,
    const float* __restrict__ bqkv, float* __restrict__ emb,
    float* __restrict__ qkv)
{
    int m  = blockIdx.x*4 + (threadIdx.x>>6);
    int ln = threadIdx.x & 63;
    float a = emb0[(size_t)m*64+ln];
    int ty = edge_types[m];
    float tb = type_emb[ty*64+ln];
    float va = 0.f, vb = 0.f;
    for (int j=0;j<64;++j) va += __shfl(a,j)  * em_w[j*64+ln];
    for (int j=0;j<64;++j) vb += __shfl(tb,j) * em_w[(64+j)*64+ln];
    float v = em_b[ln] + va + vb;
    float mu  = wave_sum(v)*(1.0f/64.0f);
    float d   = v - mu;
    float var = wave_sum(d*d)*(1.0f/64.0f);
    float e = gelu_f(d * rsqrtf(var+1e-5f) * em_g[ln] + em_bt[ln]);
    emb[(size_t)m*64+ln] = e;
    float q = bqkv[ln], k = bqkv[64+ln], vv = bqkv[128+ln];
    for (int j=0;j<64;++j){
        float ej = __shfl(e,j);
        q  += ej*wqkv[j*192+ln];
        k  += ej*wqkv[j*192+64+ln];
        vv += ej*wqkv[j*192+128+ln];
    }
    qkv[(size_t)m*192+ln]=q; qkv[(size_t)m*192+64+ln]=k; qkv[(size_t)m*192+128+ln]=vv;
}

// ---------------- K3: attention; block = (batch, head, qtile of 64) ---------
__global__ __launch_bounds__(256) void k_attn(
    const float* __restrict__ qkv, float* __restrict__ o)
{
    __shared__ float KsT[16][244], VsT[16][244];
    int blk = blockIdx.x;
    int b  = blk >> 4;
    int h  = (blk >> 2) & 3;
    int qt = blk & 3;
    int tid = threadIdx.x;
    for (int i=tid; i<NEDGE*16; i+=256){
        int r = i>>4, d = i&15;
        size_t base = ((size_t)(b*NEDGE+r))*192 + h*16 + d;
        KsT[d][r] = qkv[base+64];
        VsT[d][r] = qkv[base+128];
    }
    __syncthreads();
    int c = tid & 3, qi = tid >> 2;
    int q = qt*64 + qi;
    bool act = (q < NEDGE);
    float qv[16];
    size_t qb = ((size_t)(b*NEDGE + (act ? q : 0)))*192 + h*16;
    #pragma unroll
    for (int d=0; d<16; ++d) qv[d] = qkv[qb+d];
    float mx = -3e38f, l = 0.f, acc[16];
    #pragma unroll
    for (int d=0; d<16; ++d) acc[d]=0.f;
    for (int k=0; k<60; ++k){
        int key = 60*c + k;
        float s=0.f;
        #pragma unroll
        for (int d=0; d<16; ++d) s += qv[d]*KsT[d][key];
        s *= 0.25f;
        if (s > mx){
            float so = __expf(mx - s);
            l *= so;
            #pragma unroll
            for (int d=0; d<16; ++d) acc[d] *= so;
            mx = s;
        }
        float pp = __expf(s - mx);
        l += pp;
        #pragma unroll
        for (int d=0; d<16; ++d) acc[d] = fmaf(pp, VsT[d][key], acc[d]);
    }
    #pragma unroll
    for (int off=1; off<=2; off<<=1){
        float mo = __shfl_xor(mx, off);
        float lo = __shfl_xor(l,  off);
        float M  = fmaxf(mx, mo);
        float ss = __expf(mx - M);
        float so = __expf(mo - M);
        l = l*ss + lo*so;
        #pragma unroll
        for (int d=0; d<16; ++d)
            acc[d] = acc[d]*ss + __shfl_xor(acc[d], off)*so;
        mx = M;
    }
    if (act && c==0){
        float inv = 1.f/l;
        size_t obase = ((size_t)(b*NEDGE+q))*64 + h*16;
        #pragma unroll
        for (int d=0; d<16; ++d) o[obase+d] = acc[d]*inv;
    }
}

// ---------------- K4: out-proj+LN1+FFN+LN2 (+ optional next-layer qkv) ------
__global__ __launch_bounds__(256) void k_postattn(
    const float* __restrict__ o, const float* __restrict__ wo,
    const float* __restrict__ bo, const float* __restrict__ g1,
    const float* __restrict__ b1ln, const float* __restrict__ w1,
    const float* __restrict__ b1, const float* __restrict__ w2,
    const float* __restrict__ b2, const float* __restrict__ g2,
    const float* __restrict__ b2ln, float* __restrict__ emb,
    const float* __restrict__ wqkv, const float* __restrict__ bqkv,
    float* __restrict__ qkv)
{
    int m  = blockIdx.x*4 + (threadIdx.x>>6);
    int ln = threadIdx.x & 63;
    float ov = o[(size_t)m*64+ln];
    float r = bo[ln];
    for (int j=0;j<64;++j) r += __shfl(ov,j)*wo[j*64+ln];
    float x = emb[(size_t)m*64+ln] + r;
    float mu  = wave_sum(x)*(1.f/64.f);
    float d   = x-mu;
    float var = wave_sum(d*d)*(1.f/64.f);
    float e1 = d*rsqrtf(var+1e-5f)*g1[ln] + b1ln[ln];
    float4 bv = *(const float4*)(b1 + ln*4);
    float h[4] = {bv.x, bv.y, bv.z, bv.w};
    for (int j=0;j<64;++j){
        float ej = __shfl(e1,j);
        float4 wv = *(const float4*)(w1 + j*256 + ln*4);
        h[0] += ej*wv.x; h[1] += ej*wv.y; h[2] += ej*wv.z; h[3] += ej*wv.w;
    }
    #pragma unroll
    for (int u=0;u<4;++u) h[u]=gelu_f(h[u]);
    float f0=0.f, f1=0.f, f2=0.f, f3=0.f;
    for (int j=0;j<64;++j){
        f0 += __shfl(h[0],j) * w2[(j*4+0)*64+ln];
        f1 += __shfl(h[1],j) * w2[(j*4+1)*64+ln];
        f2 += __shfl(h[2],j) * w2[(j*4+2)*64+ln];
        f3 += __shfl(h[3],j) * w2[(j*4+3)*64+ln];
    }
    float f = b2[ln] + ((f0+f1)+(f2+f3));
    float x2 = e1 + f;
    float mu2  = wave_sum(x2)*(1.f/64.f);
    float d2   = x2-mu2;
    float var2 = wave_sum(d2*d2)*(1.f/64.f);
    float e2 = d2*rsqrtf(var2+1e-5f)*g2[ln] + b2ln[ln];
    emb[(size_t)m*64+ln] = e2;
    if (wqkv){
        float q = bqkv[ln], k = bqkv[64+ln], vv = bqkv[128+ln];
        for (int j=0;j<64;++j){
            float ej = __shfl(e2,j);
            q  += ej*wqkv[j*192+ln];
            k  += ej*wqkv[j*192+64+ln];
            vv += ej*wqkv[j*192+128+ln];
        }
        qkv[(size_t)m*192+ln]=q; qkv[(size_t)m*192+64+ln]=k; qkv[(size_t)m*192+128+ln]=vv;
    }
}

// ---------------- K5: edge head + node head fused ---------------------------
__global__ __launch_bounds__(256) void k_heads(
    const float* __restrict__ emb, const float* __restrict__ eh_w,
    const float* __restrict__ eh_b, const float* __restrict__ nm_w,
    const float* __restrict__ nm_b, const float* __restrict__ nm_g,
    const float* __restrict__ nm_bt, const float* __restrict__ nh_w,
    const float* __restrict__ nh_b, const int* __restrict__ pp,
    const int* __restrict__ xp, const int* __restrict__ yp,
    float* __restrict__ out)
{
    if (blockIdx.x < 15){
        int gid = blockIdx.x*256 + threadIdx.x;
        int m = gid>>1, c = gid&1;
        float s = eh_b[c];
        const float* e = emb + (size_t)m*64;
        #pragma unroll 8
        for (int j=0;j<64;++j) s += e[j]*eh_w[j*2+c];
        out[gid] = s;
        return;
    }
    int wid = (blockIdx.x-15)*4 + (threadIdx.x>>6);
    int ln  = threadIdx.x & 63;
    int p = pp[0], xi = xp[0], yi = yp[0];
    int nu = p-2;
    if (wid >= NBAT*nu) return;
    int b = wid / nu, r = wid % nu;
    int u=-1, cnt=0;
    for (int i=0;i<p;++i){ if (i!=xi && i!=yi){ if (cnt==r){u=i;break;} ++cnt; } }
    #define EIDX(a,v) ((a)*(p-1) + (v) - (((v)>(a))?1:0))
    int iux = EIDX(u,xi), iuy = EIDX(u,yi), ixu = EIDX(xi,u), iyu = EIDX(yi,u);
    float g0 = emb[((size_t)(b*NEDGE+iux))*64+ln];
    float g1 = emb[((size_t)(b*NEDGE+iuy))*64+ln];
    float g2 = emb[((size_t)(b*NEDGE+ixu))*64+ln];
    float g3 = emb[((size_t)(b*NEDGE+iyu))*64+ln];
    float v = nm_b[ln];
    for (int j=0;j<64;++j) v += __shfl(g0,j)*nm_w[j*64+ln];
    for (int j=0;j<64;++j) v += __shfl(g1,j)*nm_w[(64+j)*64+ln];
    for (int j=0;j<64;++j) v += __shfl(g2,j)*nm_w[(128+j)*64+ln];
    for (int j=0;j<64;++j) v += __shfl(g3,j)*nm_w[(192+j)*64+ln];
    float mu  = wave_sum(v)*(1.f/64.f);
    float d   = v-mu;
    float var = wave_sum(d*d)*(1.f/64.f);
    float node = gelu_f(d*rsqrtf(var+1e-5f)*nm_g[ln] + nm_bt[ln]);
    float pl[8];
    #pragma unroll
    for (int c=0;c<8;++c) pl[c] = node*nh_w[ln*8+c];
    #pragma unroll
    for (int off=32; off>0; off>>=1)
        #pragma unroll
        for (int c=0;c<8;++c) pl[c] += __shfl_xor(pl[c], off);
    if (ln==0){
        #pragma unroll
        for (int c=0;c<8;++c) out[MROWS*2 + ((size_t)wid)*8 + c] = pl[c] + nh_b[c];
    }
}

extern "C" void kernel_launch(void* const* d_in, const int* in_sizes, int n_in,
                              void* d_out, int out_size, void* d_ws, size_t ws_size,
                              hipStream_t stream)
{
    const float* edge_data = (const float*)d_in[0];
    const int*   edge_types= (const int*)d_in[1];
    const int* pp = (const int*)d_in[3];
    const int* xp = (const int*)d_in[4];
    const int* yp = (const int*)d_in[5];
    const float* stem_w=(const float*)d_in[6];
    const float* stem_b=(const float*)d_in[7];
    const float* conv_w=(const float*)d_in[8];
    const float* gn_g=(const float*)d_in[9];
    const float* gn_b=(const float*)d_in[10];
    const float* type_emb=(const float*)d_in[11];
    const float* em_w=(const float*)d_in[12];
    const float* em_b=(const float*)d_in[13];
    const float* em_g=(const float*)d_in[14];
    const float* em_bt=(const float*)d_in[15];
    const float* a_wqkv=(const float*)d_in[16];
    const float* a_bqkv=(const float*)d_in[17];
    const float* a_wo=(const float*)d_in[18];
    const float* a_bo=(const float*)d_in[19];
    const float* ln1_g=(const float*)d_in[20];
    const float* ln1_b=(const float*)d_in[21];
    const float* ff_w1=(const float*)d_in[22];
    const float* ff_b1=(const float*)d_in[23];
    const float* ff_w2=(const float*)d_in[24];
    const float* ff_b2=(const float*)d_in[25];
    const float* ln2_g=(const float*)d_in[26];
    const float* ln2_b=(const float*)d_in[27];
    const float* eh_w=(const float*)d_in[28];
    const float* eh_b=(const float*)d_in[29];
    const float* nm_w=(const float*)d_in[30];
    const float* nm_b=(const float*)d_in[31];
    const float* nm_g=(const float*)d_in[32];
    const float* nm_bt=(const float*)d_in[33];
    const float* nh_w=(const float*)d_in[34];
    const float* nh_b=(const float*)d_in[35];
    (void)in_sizes; (void)n_in; (void)out_size; (void)ws_size;

    unsigned short* wfrag = (unsigned short*)d_ws;
    float* wsf  = (float*)d_ws;
    float* emb  = wsf + 30720;
    float* qkvb = emb + 122880;
    float* obuf = qkvb + 368640;
    float* outp = (float*)d_out;

    k_wprep   <<<30, 256, 0, stream>>>(conv_w, wfrag);
    k_extract <<<MROWS, 512, 0, stream>>>(edge_data, stem_w, stem_b, wfrag, gn_g, gn_b, emb);
    k_mergeqkv<<<MROWS/4, 256, 0, stream>>>(emb, edge_types, type_emb, em_w, em_b, em_g,
                                            em_bt, a_wqkv, a_bqkv, emb, qkvb);
    // layer 0
    k_attn    <<<NBAT*16, 256, 0, stream>>>(qkvb, obuf);
    k_postattn<<<MROWS/4, 256, 0, stream>>>(obuf, a_wo, a_bo, ln1_g, ln1_b,
                                            ff_w1, ff_b1, ff_w2, ff_b2, ln2_g, ln2_b,
                                            emb, a_wqkv + (size_t)64*192, a_bqkv + 192, qkvb);
    // layer 1
    k_attn    <<<NBAT*16, 256, 0, stream>>>(qkvb, obuf);
    k_postattn<<<MROWS/4, 256, 0, stream>>>(obuf, a_wo + (size_t)64*64, a_bo + 64,
                                            ln1_g + 64, ln1_b + 64,
                                            ff_w1 + (size_t)64*256, ff_b1 + 256,
                                            ff_w2 + (size_t)256*64, ff_b2 + 64,
                                            ln2_g + 64, ln2_b + 64,
                                            emb, (const float*)nullptr, (const float*)nullptr, qkvb);
    k_heads   <<<43, 256, 0, stream>>>(emb, eh_w, eh_b, nm_w, nm_b, nm_g, nm_bt,
                                       nh_w, nh_b, pp, xp, yp, outp);
}

// Round 8
// 257.937 us; speedup vs baseline: 1.0944x; 1.0876x over previous
//
#include <hip/hip_runtime.h>
#include <hip/hip_bf16.h>
#include <math.h>

// Model constants (fixed by shapes)
#define NEDGE 240
#define NBAT  8
#define MROWS 1920   // NBAT*NEDGE
#define NPTS  256
#define CIN   5

typedef __attribute__((ext_vector_type(8))) short  bf16x8;
typedef __attribute__((ext_vector_type(4))) float  f32x4;

// tanh-form GELU via sigmoid on exp2: gelu(x) ~= x * e/(e+1),
// e = 2^(x*(c1 + c2*x^2)), constants pre-scaled by log2(e).
// Post-clamp s<=126 keeps e finite (ratio->1 = correct limit).
__device__ __forceinline__ float gelu_f(float x){
    float s = x * fmaf(0.10294322f, x*x, 2.30220807f);
    float e = __builtin_amdgcn_exp2f(fminf(s, 126.f));
    float r = __builtin_amdgcn_rcpf(e + 1.0f);
    return x*e*r;
}
__device__ __forceinline__ float wave_sum(float v){
    #pragma unroll
    for (int off=32; off>0; off>>=1) v += __shfl_xor(v, off);
    return v;
}
// wave-uniform broadcast of lane l (compile-time l) -> v_readlane, no DS pipe
__device__ __forceinline__ float bcast(float v, int l){
    return __int_as_float(__builtin_amdgcn_readlane(__float_as_int(v), l));
}
__device__ __forceinline__ unsigned short f2bf(float x){   // RNE f32->bf16
    unsigned int u = __float_as_uint(x);
    return (unsigned short)((u + 0x7FFFu + ((u>>16)&1u)) >> 16);
}
__device__ __forceinline__ unsigned pack_bf2(float lo, float hi){
    __hip_bfloat162 t = __float22bfloat162_rn(make_float2(lo, hi));
    union { __hip_bfloat162 b; unsigned u; } cv; cv.b = t;
    return cv.u;
}

// ---------------- K0: pre-convert conv weights to bf16 MFMA A-fragments ----
// frag id f = layer*24 + (ob*3+tap)*2+q ; lane m=lane&15 (out ch in o-block),
// k = 32q + 8*(lane>>4) + e (in ch). wf[(f*64+lane)*8+e]
__global__ __launch_bounds__(256) void k_wprep(
    const float* __restrict__ conv_w, unsigned short* __restrict__ wf)
{
    int t = blockIdx.x*256 + threadIdx.x;
    if (t >= 120*64) return;
    int lane = t & 63, f = t >> 6;
    int q = f & 1, tap = (f>>1)%3, ob = (f/6)&3, layer = f/24;
    int o = 16*ob + (lane&15);
    int ibase = 32*q + 8*(lane>>4);
    #pragma unroll
    for (int e=0;e<8;++e){
        int i = ibase + e;
        float w = conv_w[(((size_t)layer*64 + o)*64 + i)*3 + tap];
        wf[(size_t)t*8 + e] = f2bf(w);
    }
}

// ---------------- K1: stem + 5 residual conv/GN/GELU blocks + mean pool ----
// R5 structure (proven 166us): one block (512 thr) per edge; hbf[258][64] bf16
// swizzled; wave w owns o-block wb=w&3 x 128 cols (colbase=128*(w>>2)).
// A-frags (6/layer) in regs, reloaded per layer under the epilogue.
// Changes vs R5: folded GN (1 fma/value), exp2-gelu, gamma/beta via global f4.
__global__ __launch_bounds__(512, 2) void k_extract(
    const float* __restrict__ edge_data, const float* __restrict__ stem_w,
    const float* __restrict__ stem_b, const unsigned short* __restrict__ wf,
    const float* __restrict__ gn_g, const float* __restrict__ gn_b,
    float* __restrict__ emb0)
{
    __shared__ unsigned short hbf[258*64];    // 33024 B
    __shared__ float redg[8][2][2];           // [wave][half][{sum,sumsq}]
    __shared__ float redp[8][16];
    const int m = blockIdx.x, tid = threadIdx.x;
    const int w = tid>>6, lane = tid&63;
    const int g = (lane>>4)&3, l15 = lane&15;
    const int wb = w&3, colbase = 128*(w>>2);
    const bf16x8* wfp = (const bf16x8*)wf;

    // A-frags for layer 0 (issue early; land during stem)
    bf16x8 A[6];
    #pragma unroll
    for (int fq=0; fq<6; ++fq)
        A[fq] = wfp[(size_t)(wb*6 + fq)*64 + lane];

    // ---- loop-invariant LDS addresses
    const int i0 = 16*wb + 4*g;
    unsigned raddr[3][2];
    {
        unsigned clb = (unsigned)((colbase + l15)*128);
        #pragma unroll
        for (int tap=0;tap<3;++tap)
            #pragma unroll
            for (int q=0;q<2;++q)
                raddr[tap][q] = clb + (unsigned)(((4*q+g) ^ ((l15+tap)&7))<<4);
    }
    const unsigned wb0 = (unsigned)((colbase + l15 + 1)*128
                       + (((i0>>3) ^ ((l15+1)&7))<<4) + ((i0&7)<<1));

    float h[8][4];   // [nbl][j] f32 master

    // ---- stem
    {
        const float* xs = edge_data + (size_t)m*CIN*NPTS;
        float sw[4][6];
        #pragma unroll
        for (int j=0;j<4;++j){
            int o = i0 + j;
            #pragma unroll
            for (int c=0;c<5;++c) sw[j][c] = stem_w[c*64+o];
            sw[j][5] = stem_b[o];
        }
        #pragma unroll
        for (int nbl=0;nbl<8;++nbl){
            int n = colbase + 16*nbl + l15;
            float x0=xs[n], x1=xs[NPTS+n], x2=xs[2*NPTS+n],
                  x3=xs[3*NPTS+n], x4=xs[4*NPTS+n];
            #pragma unroll
            for (int j=0;j<4;++j)
                h[nbl][j] = sw[j][5] + x0*sw[j][0] + x1*sw[j][1]
                          + x2*sw[j][2] + x3*sw[j][3] + x4*sw[j][4];
            unsigned long long pk = (unsigned long long)pack_bf2(h[nbl][0], h[nbl][1])
                                  | ((unsigned long long)pack_bf2(h[nbl][2], h[nbl][3]) << 32);
            *(unsigned long long*)((char*)hbf + wb0 + 2048*nbl) = pk;
        }
    }
    // zero halo rows n'=0 and n'=257
    if (tid < 32)       ((unsigned int*)hbf)[tid] = 0u;
    else if (tid < 64)  ((unsigned int*)hbf)[257*32 + tid - 32] = 0u;
    __syncthreads();

    // ---- 5 residual conv blocks (MFMA)
    #pragma unroll 1
    for (int layer=0; layer<5; ++layer){
        f32x4 acc[8];
        #pragma unroll
        for (int nbl=0;nbl<8;++nbl) acc[nbl] = (f32x4){0.f,0.f,0.f,0.f};

        #pragma unroll
        for (int tap=0; tap<3; ++tap)
        #pragma unroll
        for (int q=0; q<2; ++q){
            #pragma unroll
            for (int nbl=0;nbl<8;++nbl){
                bf16x8 Bv = *(const bf16x8*)((const char*)hbf
                              + raddr[tap][q] + (2048*nbl + 128*tap));
                acc[nbl] = __builtin_amdgcn_mfma_f32_16x16x32_bf16(
                               A[tap*2+q], Bv, acc[nbl], 0,0,0);
            }
        }

        // GroupNorm stats: thread's 32 values all in group 2*wb + (g>>1)
        float s=0.f, sq=0.f;
        #pragma unroll
        for (int nbl=0;nbl<8;++nbl)
            #pragma unroll
            for (int j=0;j<4;++j){ float v=acc[nbl][j]; s+=v; sq+=v*v; }
        #pragma unroll
        for (int off=1; off<=16; off<<=1){
            s  += __shfl_xor(s,  off);
            sq += __shfl_xor(sq, off);
        }
        if ((lane&31)==0){
            redg[w][lane>>5][0] = s;
            redg[w][lane>>5][1] = sq;
        }
        __syncthreads();   // #1: MFMA reads of hbf done; redg published

        // reload A with next layer's frags (regs dead; lands under epilogue)
        if (layer < 4){
            #pragma unroll
            for (int fq=0; fq<6; ++fq)
                A[fq] = wfp[(size_t)((layer+1)*24 + wb*6 + fq)*64 + lane];
        }

        int hf = g>>1;
        float S = redg[wb][hf][0] + redg[wb+4][hf][0];
        float Q = redg[wb][hf][1] + redg[wb+4][hf][1];
        float mu = S*(1.f/2048.f);
        float rstd = rsqrtf(Q*(1.f/2048.f) - mu*mu + 1e-5f);

        // GN folded to 1 FMA per value; gamma/beta via global float4 (VMEM)
        float4 gv = *(const float4*)(gn_g + layer*64 + i0);
        float4 bv = *(const float4*)(gn_b + layer*64 + i0);
        float K1x=rstd*gv.x, K1y=rstd*gv.y, K1z=rstd*gv.z, K1w=rstd*gv.w;
        float K2x=fmaf(-mu,K1x,bv.x), K2y=fmaf(-mu,K1y,bv.y),
              K2z=fmaf(-mu,K1z,bv.z), K2w=fmaf(-mu,K1w,bv.w);
        #pragma unroll
        for (int nbl=0;nbl<8;++nbl){
            h[nbl][0] += gelu_f(fmaf(acc[nbl][0], K1x, K2x));
            h[nbl][1] += gelu_f(fmaf(acc[nbl][1], K1y, K2y));
            h[nbl][2] += gelu_f(fmaf(acc[nbl][2], K1z, K2z));
            h[nbl][3] += gelu_f(fmaf(acc[nbl][3], K1w, K2w));
        }
        if (layer < 4){
            #pragma unroll
            for (int nbl=0;nbl<8;++nbl){
                unsigned long long pk = (unsigned long long)pack_bf2(h[nbl][0], h[nbl][1])
                                      | ((unsigned long long)pack_bf2(h[nbl][2], h[nbl][3]) << 32);
                *(unsigned long long*)((char*)hbf + wb0 + 2048*nbl) = pk;
            }
            __syncthreads();   // #2: hbf ready for next layer
        }
    }

    // ---- mean pool over N (h in registers)
    float p[4];
    #pragma unroll
    for (int j=0;j<4;++j){
        float a = 0.f;
        #pragma unroll
        for (int nbl=0;nbl<8;++nbl) a += h[nbl][j];
        p[j] = a;
    }
    #pragma unroll
    for (int off=1; off<=8; off<<=1)
        #pragma unroll
        for (int j=0;j<4;++j) p[j] += __shfl_xor(p[j], off);
    if (l15==0){
        #pragma unroll
        for (int j=0;j<4;++j) redp[w][4*g+j] = p[j];
    }
    __syncthreads();
    if (tid < 64){
        int ob = tid>>4, r = tid&15;
        emb0[(size_t)m*64+tid] = (redp[ob][r] + redp[ob+4][r]) * (1.0f/256.0f);
    }
}

// ---------------- K2: merge (concat @ em_w -> LN -> gelu) + qkv (layer 0) --
// fully unrolled GEMV loops with v_readlane broadcasts (no DS, batched loads)
__global__ __launch_bounds__(256) void k_mergeqkv(
    const float* __restrict__ emb0, const int* __restrict__ edge_types,
    const float* __restrict__ type_emb, const float* __restrict__ em_w,
    const float* __restrict__ em_b, const float* __restrict__ em_g,
    const float* __restrict__ em_bt, const float* __restrict__ wqkv,
    const float* __restrict__ bqkv, float* __restrict__ emb,
    float* __restrict__ qkv)
{
    int m  = blockIdx.x*4 + (threadIdx.x>>6);
    int ln = threadIdx.x & 63;
    float a = emb0[(size_t)m*64+ln];
    int ty = edge_types[m];
    float tb = type_emb[ty*64+ln];
    float va = 0.f, vb = 0.f;
    #pragma unroll
    for (int j=0;j<64;++j) va += bcast(a,j)  * em_w[j*64+ln];
    #pragma unroll
    for (int j=0;j<64;++j) vb += bcast(tb,j) * em_w[(64+j)*64+ln];
    float v = em_b[ln] + va + vb;
    float mu  = wave_sum(v)*(1.0f/64.0f);
    float d   = v - mu;
    float var = wave_sum(d*d)*(1.0f/64.0f);
    float e = gelu_f(d * rsqrtf(var+1e-5f) * em_g[ln] + em_bt[ln]);
    emb[(size_t)m*64+ln] = e;
    float q = bqkv[ln], k = bqkv[64+ln], vv = bqkv[128+ln];
    #pragma unroll
    for (int j=0;j<64;++j){
        float ej = bcast(e,j);
        q  += ej*wqkv[j*192+ln];
        k  += ej*wqkv[j*192+64+ln];
        vv += ej*wqkv[j*192+128+ln];
    }
    qkv[(size_t)m*192+ln]=q; qkv[(size_t)m*192+64+ln]=k; qkv[(size_t)m*192+128+ln]=vv;
}

// ---------------- K3: attention; block = (batch, head, qtile of 64) ---------
__global__ __launch_bounds__(256) void k_attn(
    const float* __restrict__ qkv, float* __restrict__ o)
{
    __shared__ float KsT[16][244], VsT[16][244];
    int blk = blockIdx.x;
    int b  = blk >> 4;
    int h  = (blk >> 2) & 3;
    int qt = blk & 3;
    int tid = threadIdx.x;
    for (int i=tid; i<NEDGE*16; i+=256){
        int r = i>>4, d = i&15;
        size_t base = ((size_t)(b*NEDGE+r))*192 + h*16 + d;
        KsT[d][r] = qkv[base+64];
        VsT[d][r] = qkv[base+128];
    }
    __syncthreads();
    int c = tid & 3, qi = tid >> 2;
    int q = qt*64 + qi;
    bool act = (q < NEDGE);
    float qv[16];
    size_t qb = ((size_t)(b*NEDGE + (act ? q : 0)))*192 + h*16;
    #pragma unroll
    for (int d=0; d<16; ++d) qv[d] = qkv[qb+d];
    float mx = -3e38f, l = 0.f, acc[16];
    #pragma unroll
    for (int d=0; d<16; ++d) acc[d]=0.f;
    for (int k=0; k<60; ++k){
        int key = 60*c + k;
        float s=0.f;
        #pragma unroll
        for (int d=0; d<16; ++d) s += qv[d]*KsT[d][key];
        s *= 0.25f;
        if (s > mx){
            float so = __expf(mx - s);
            l *= so;
            #pragma unroll
            for (int d=0; d<16; ++d) acc[d] *= so;
            mx = s;
        }
        float pp = __expf(s - mx);
        l += pp;
        #pragma unroll
        for (int d=0; d<16; ++d) acc[d] = fmaf(pp, VsT[d][key], acc[d]);
    }
    #pragma unroll
    for (int off=1; off<=2; off<<=1){
        float mo = __shfl_xor(mx, off);
        float lo = __shfl_xor(l,  off);
        float M  = fmaxf(mx, mo);
        float ss = __expf(mx - M);
        float so = __expf(mo - M);
        l = l*ss + lo*so;
        #pragma unroll
        for (int d=0; d<16; ++d)
            acc[d] = acc[d]*ss + __shfl_xor(acc[d], off)*so;
        mx = M;
    }
    if (act && c==0){
        float inv = 1.f/l;
        size_t obase = ((size_t)(b*NEDGE+q))*64 + h*16;
        #pragma unroll
        for (int d=0; d<16; ++d) o[obase+d] = acc[d]*inv;
    }
}

// ---------------- K4: out-proj+LN1+FFN+LN2 (+ next-layer qkv | edge head) ---
__global__ __launch_bounds__(256) void k_postattn(
    const float* __restrict__ o, const float* __restrict__ wo,
    const float* __restrict__ bo, const float* __restrict__ g1,
    const float* __restrict__ b1ln, const float* __restrict__ w1,
    const float* __restrict__ b1, const float* __restrict__ w2,
    const float* __restrict__ b2, const float* __restrict__ g2,
    const float* __restrict__ b2ln, float* __restrict__ emb,
    const float* __restrict__ wqkv, const float* __restrict__ bqkv,
    float* __restrict__ qkv, const float* __restrict__ eh_w,
    const float* __restrict__ eh_b, float* __restrict__ eout)
{
    int m  = blockIdx.x*4 + (threadIdx.x>>6);
    int ln = threadIdx.x & 63;
    float ov = o[(size_t)m*64+ln];
    float r = bo[ln];
    #pragma unroll
    for (int j=0;j<64;++j) r += bcast(ov,j)*wo[j*64+ln];
    float x = emb[(size_t)m*64+ln] + r;
    float mu  = wave_sum(x)*(1.f/64.f);
    float d   = x-mu;
    float var = wave_sum(d*d)*(1.f/64.f);
    float e1 = d*rsqrtf(var+1e-5f)*g1[ln] + b1ln[ln];
    float4 bv = *(const float4*)(b1 + ln*4);
    float h[4] = {bv.x, bv.y, bv.z, bv.w};
    #pragma unroll
    for (int j=0;j<64;++j){
        float ej = bcast(e1,j);
        float4 wv = *(const float4*)(w1 + j*256 + ln*4);
        h[0] += ej*wv.x; h[1] += ej*wv.y; h[2] += ej*wv.z; h[3] += ej*wv.w;
    }
    #pragma unroll
    for (int u=0;u<4;++u) h[u]=gelu_f(h[u]);
    float f0=0.f, f1=0.f, f2=0.f, f3=0.f;
    #pragma unroll
    for (int j=0;j<64;++j){
        f0 += bcast(h[0],j) * w2[(j*4+0)*64+ln];
        f1 += bcast(h[1],j) * w2[(j*4+1)*64+ln];
        f2 += bcast(h[2],j) * w2[(j*4+2)*64+ln];
        f3 += bcast(h[3],j) * w2[(j*4+3)*64+ln];
    }
    float f = b2[ln] + ((f0+f1)+(f2+f3));
    float x2 = e1 + f;
    float mu2  = wave_sum(x2)*(1.f/64.f);
    float d2   = x2-mu2;
    float var2 = wave_sum(d2*d2)*(1.f/64.f);
    float e2 = d2*rsqrtf(var2+1e-5f)*g2[ln] + b2ln[ln];
    emb[(size_t)m*64+ln] = e2;
    if (wqkv){
        float q = bqkv[ln], k = bqkv[64+ln], vv = bqkv[128+ln];
        #pragma unroll
        for (int j=0;j<64;++j){
            float ej = bcast(e2,j);
            q  += ej*wqkv[j*192+ln];
            k  += ej*wqkv[j*192+64+ln];
            vv += ej*wqkv[j*192+128+ln];
        }
        qkv[(size_t)m*192+ln]=q; qkv[(size_t)m*192+64+ln]=k; qkv[(size_t)m*192+128+ln]=vv;
    }
    if (eh_w){   // fused edge head (layer 1): logits = e2 @ eh_w + eh_b
        float p0 = e2*eh_w[ln*2+0];
        float p1 = e2*eh_w[ln*2+1];
        p0 = wave_sum(p0); p1 = wave_sum(p1);
        if (ln==0){
            eout[(size_t)m*2+0] = p0 + eh_b[0];
            eout[(size_t)m*2+1] = p1 + eh_b[1];
        }
    }
}

// ---------------- K5: node head ---------------------------------------------
__global__ __launch_bounds__(256) void k_nodehead(
    const float* __restrict__ emb, const float* __restrict__ nm_w,
    const float* __restrict__ nm_b, const float* __restrict__ nm_g,
    const float* __restrict__ nm_bt, const float* __restrict__ nh_w,
    const float* __restrict__ nh_b, const int* __restrict__ pp,
    const int* __restrict__ xp, const int* __restrict__ yp,
    float* __restrict__ out)
{
    int wid = blockIdx.x*4 + (threadIdx.x>>6);
    int ln  = threadIdx.x & 63;
    int p = pp[0], xi = xp[0], yi = yp[0];
    int nu = p-2;
    if (wid >= NBAT*nu) return;
    int b = wid / nu, r = wid % nu;
    int u=-1, cnt=0;
    for (int i=0;i<p;++i){ if (i!=xi && i!=yi){ if (cnt==r){u=i;break;} ++cnt; } }
    #define EIDX(a,v) ((a)*(p-1) + (v) - (((v)>(a))?1:0))
    int iux = EIDX(u,xi), iuy = EIDX(u,yi), ixu = EIDX(xi,u), iyu = EIDX(yi,u);
    float g0 = emb[((size_t)(b*NEDGE+iux))*64+ln];
    float g1 = emb[((size_t)(b*NEDGE+iuy))*64+ln];
    float g2 = emb[((size_t)(b*NEDGE+ixu))*64+ln];
    float g3 = emb[((size_t)(b*NEDGE+iyu))*64+ln];
    float v = nm_b[ln];
    #pragma unroll
    for (int j=0;j<64;++j) v += bcast(g0,j)*nm_w[j*64+ln];
    #pragma unroll
    for (int j=0;j<64;++j) v += bcast(g1,j)*nm_w[(64+j)*64+ln];
    #pragma unroll
    for (int j=0;j<64;++j) v += bcast(g2,j)*nm_w[(128+j)*64+ln];
    #pragma unroll
    for (int j=0;j<64;++j) v += bcast(g3,j)*nm_w[(192+j)*64+ln];
    float mu  = wave_sum(v)*(1.f/64.f);
    float d   = v-mu;
    float var = wave_sum(d*d)*(1.f/64.f);
    float node = gelu_f(d*rsqrtf(var+1e-5f)*nm_g[ln] + nm_bt[ln]);
    float pl[8];
    #pragma unroll
    for (int c=0;c<8;++c) pl[c] = node*nh_w[ln*8+c];
    #pragma unroll
    for (int off=32; off>0; off>>=1)
        #pragma unroll
        for (int c=0;c<8;++c) pl[c] += __shfl_xor(pl[c], off);
    if (ln==0){
        #pragma unroll
        for (int c=0;c<8;++c) out[MROWS*2 + ((size_t)wid)*8 + c] = pl[c] + nh_b[c];
    }
}

extern "C" void kernel_launch(void* const* d_in, const int* in_sizes, int n_in,
                              void* d_out, int out_size, void* d_ws, size_t ws_size,
                              hipStream_t stream)
{
    const float* edge_data = (const float*)d_in[0];
    const int*   edge_types= (const int*)d_in[1];
    const int* pp = (const int*)d_in[3];
    const int* xp = (const int*)d_in[4];
    const int* yp = (const int*)d_in[5];
    const float* stem_w=(const float*)d_in[6];
    const float* stem_b=(const float*)d_in[7];
    const float* conv_w=(const float*)d_in[8];
    const float* gn_g=(const float*)d_in[9];
    const float* gn_b=(const float*)d_in[10];
    const float* type_emb=(const float*)d_in[11];
    const float* em_w=(const float*)d_in[12];
    const float* em_b=(const float*)d_in[13];
    const float* em_g=(const float*)d_in[14];
    const float* em_bt=(const float*)d_in[15];
    const float* a_wqkv=(const float*)d_in[16];
    const float* a_bqkv=(const float*)d_in[17];
    const float* a_wo=(const float*)d_in[18];
    const float* a_bo=(const float*)d_in[19];
    const float* ln1_g=(const float*)d_in[20];
    const float* ln1_b=(const float*)d_in[21];
    const float* ff_w1=(const float*)d_in[22];
    const float* ff_b1=(const float*)d_in[23];
    const float* ff_w2=(const float*)d_in[24];
    const float* ff_b2=(const float*)d_in[25];
    const float* ln2_g=(const float*)d_in[26];
    const float* ln2_b=(const float*)d_in[27];
    const float* eh_w=(const float*)d_in[28];
    const float* eh_b=(const float*)d_in[29];
    const float* nm_w=(const float*)d_in[30];
    const float* nm_b=(const float*)d_in[31];
    const float* nm_g=(const float*)d_in[32];
    const float* nm_bt=(const float*)d_in[33];
    const float* nh_w=(const float*)d_in[34];
    const float* nh_b=(const float*)d_in[35];
    (void)in_sizes; (void)n_in; (void)out_size; (void)ws_size;

    unsigned short* wfrag = (unsigned short*)d_ws;
    float* wsf  = (float*)d_ws;
    float* emb  = wsf + 30720;
    float* qkvb = emb + 122880;
    float* obuf = qkvb + 368640;
    float* outp = (float*)d_out;

    k_wprep   <<<30, 256, 0, stream>>>(conv_w, wfrag);
    k_extract <<<MROWS, 512, 0, stream>>>(edge_data, stem_w, stem_b, wfrag, gn_g, gn_b, emb);
    k_mergeqkv<<<MROWS/4, 256, 0, stream>>>(emb, edge_types, type_emb, em_w, em_b, em_g,
                                            em_bt, a_wqkv, a_bqkv, emb, qkvb);
    // layer 0
    k_attn    <<<NBAT*16, 256, 0, stream>>>(qkvb, obuf);
    k_postattn<<<MROWS/4, 256, 0, stream>>>(obuf, a_wo, a_bo, ln1_g, ln1_b,
                                            ff_w1, ff_b1, ff_w2, ff_b2, ln2_g, ln2_b,
                                            emb, a_wqkv + (size_t)64*192, a_bqkv + 192, qkvb,
                                            (const float*)nullptr, (const float*)nullptr, (float*)nullptr);
    // layer 1 (+ fused edge head)
    k_attn    <<<NBAT*16, 256, 0, stream>>>(qkvb, obuf);
    k_postattn<<<MROWS/4, 256, 0, stream>>>(obuf, a_wo + (size_t)64*64, a_bo + 64,
                                            ln1_g + 64, ln1_b + 64,
                                            ff_w1 + (size_t)64*256, ff_b1 + 256,
                                            ff_w2 + (size_t)256*64, ff_b2 + 64,
                                            ln2_g + 64, ln2_b + 64,
                                            emb, (const float*)nullptr, (const float*)nullptr, qkvb,
                                            eh_w, eh_b, outp);
    k_nodehead<<<28, 256, 0, stream>>>(emb, nm_w, nm_b, nm_g, nm_bt,
                                       nh_w, nh_b, pp, xp, yp, outp);
}